// Round 1
// baseline (377.787 us; speedup 1.0000x reference)
//
#include <hip/hip_runtime.h>
#include <cstdint>
#include <cstddef>

// GLA layer: B=4, T=4096, D=1024, H=16, S=64
// fp16 pipeline, packed weights (a rows | interleaved bg/v rows).
// GEMMs = 256x256 8-phase template (16x16x32 MFMA, 8 waves, BK=64,
// double-buffered 128KB LDS, counted vmcnt(8), setprio, XCD swizzle).
// GEMM1 epilogue: a = sigmoid(.), bv = sigmoid(.)*v (lane-pair shfl),
// LDS-staged f16x8 coalesced stores. Scan: 128 chunks x 32 steps,
// segment-parallel pass2. GEMM2 -> y fp32 direct stores.

typedef _Float16 f16;
typedef _Float16 f16x2 __attribute__((ext_vector_type(2)));
typedef _Float16 f16x8 __attribute__((ext_vector_type(8)));
typedef float    f32x4 __attribute__((ext_vector_type(4)));

__device__ __forceinline__ void gload_lds16(const void* g, void* l) {
  __builtin_amdgcn_global_load_lds(
      (const __attribute__((address_space(1))) void*)g,
      (__attribute__((address_space(3))) void*)l, 16, 0, 0);
}

__device__ __forceinline__ float sigmoidf_(float x) {
  return 1.0f / (1.0f + __expf(-x));
}

// ---------------- fused cast+pack fp32 -> fp16 ----------------
__global__ __launch_bounds__(256) void cast_pack(
    const float* __restrict__ x, const float* __restrict__ gw,
    const float* __restrict__ vw, const float* __restrict__ ow,
    f16* __restrict__ xh, f16* __restrict__ wgv, f16* __restrict__ owb) {
  const int XG = 2097152, GG = 262144, VG = 131072, OG = 131072;
  int id = blockIdx.x * 256 + threadIdx.x;
  const float* src;
  f16* dst;
  if (id < XG) {
    src = x + (size_t)id * 8;
    dst = xh + (size_t)id * 8;
  } else if (id < XG + GG) {
    int g = id - XG;
    int row = g >> 7, col = g & 127;
    int drow = (row < 1024) ? row : (1024 + 2 * (row - 1024));
    src = gw + ((size_t)row << 10) + col * 8;
    dst = wgv + ((size_t)drow << 10) + col * 8;
  } else if (id < XG + GG + VG) {
    int g = id - XG - GG;
    int row = g >> 7, col = g & 127;
    int drow = 1024 + 2 * row + 1;
    src = vw + ((size_t)row << 10) + col * 8;
    dst = wgv + ((size_t)drow << 10) + col * 8;
  } else if (id < XG + GG + VG + OG) {
    int g = id - XG - GG - VG;
    src = ow + (size_t)g * 8;
    dst = owb + (size_t)g * 8;
  } else {
    return;
  }
  float4 v0 = ((const float4*)src)[0], v1 = ((const float4*)src)[1];
  f16x8 o;
  o[0] = (f16)v0.x; o[1] = (f16)v0.y; o[2] = (f16)v0.z; o[3] = (f16)v0.w;
  o[4] = (f16)v1.x; o[5] = (f16)v1.y; o[6] = (f16)v1.z; o[7] = (f16)v1.w;
  *(f16x8*)dst = o;
}

// ---- 256x256 8-phase fp16 MFMA GEMM: C[N,M] = A[N,K] * B[M,K]^T ----
// 8 waves (2 token-halves x 4 channel-quarters), per-wave 128x64 output.
// 16x16x32 MFMA. BK=64, staged as k-halves of 32. LDS 128KB (2 bufs).
// LDS layout per (buf,khalf): slot(row,oct) = row*4 + (oct ^ ((row>>1)&3)),
// 16B slots, achieved via pre-swizzled global source (gload_lds is linear).
template <int EPI>
__global__ __launch_bounds__(512, 2) void gemm256(
    const f16* __restrict__ A, const f16* __restrict__ Bw,
    const float* __restrict__ gate_b, void* __restrict__ o0v,
    void* __restrict__ o1v, int Mtiles) {
  constexpr int K = 1024;
  __shared__ __align__(16) f16 SH[65536];  // 128 KiB
  f16* LA = SH;          // 2 x (2 khalf x 8192 f16) = 32768 f16
  f16* LB = SH + 32768;

  const int tid  = threadIdx.x;
  const int lane = tid & 63;
  const int l15  = lane & 15;
  const int oct4 = lane >> 4;   // k-octet within a 32-wide kstep
  const int wid  = tid >> 6;
  const int wr   = wid >> 2;    // 0..1 token half
  const int wc   = wid & 3;     // 0..3 channel quarter

  // bijective XCD swizzle (grid % 8 == 0 for both launches)
  const int nwg = gridDim.x;
  const int bid = blockIdx.x;
  const int swz = (bid & 7) * (nwg >> 3) + (bid >> 3);
  const int m0 = (swz % Mtiles) * 256;
  const int n0 = (swz / Mtiles) * 256;

  // staging addresses: thread covers (row=tid>>2, physOct=tid&3), j=1 -> row+128
  const int srow = tid >> 2;
  const int soct = (tid & 3) ^ ((srow >> 1) & 3);  // swizzled source octet
  const f16* Ag = A  + (size_t)(n0 + srow) * K + soct * 8;
  const f16* Bg = Bw + (size_t)(m0 + srow) * K + soct * 8;
  f16* Al = LA + tid * 8;  // + buf*16384 + khalf*8192 ; j=1: +4096
  f16* Bl = LB + tid * 8;

  // fragment read slot bases (swz independent of mm/nn: +16 rows = +64 slots)
  const int fswz  = oct4 ^ ((l15 >> 1) & 3);
  const int aslot = (wr * 128 + l15) * 4 + fswz;
  const int bslot = (wc * 64 + l15) * 4 + fswz;

  f32x4 acc[8][4];
#pragma unroll
  for (int mm = 0; mm < 8; ++mm)
#pragma unroll
    for (int nn = 0; nn < 4; ++nn)
#pragma unroll
      for (int e = 0; e < 4; ++e) acc[mm][nn][e] = 0.f;

#define STAGE_A(tl, kh)                                          \
  do {                                                           \
    const f16* s_ = Ag + (tl) * 64 + (kh) * 32;                  \
    f16* d_ = Al + ((tl) & 1) * 16384 + (kh) * 8192;             \
    gload_lds16(s_, d_);                                         \
    gload_lds16(s_ + 128 * K, d_ + 4096);                        \
  } while (0)
#define STAGE_B(tl, kh)                                          \
  do {                                                           \
    const f16* s_ = Bg + (tl) * 64 + (kh) * 32;                  \
    f16* d_ = Bl + ((tl) & 1) * 16384 + (kh) * 8192;             \
    gload_lds16(s_, d_);                                         \
    gload_lds16(s_ + 128 * K, d_ + 4096);                        \
  } while (0)

  // prologue: tile0 k0, tile0 k1, tile1 k0 (12 loads in flight)
  STAGE_A(0, 0); STAGE_B(0, 0);
  STAGE_A(0, 1); STAGE_B(0, 1);
  STAGE_A(1, 0); STAGE_B(1, 0);
  asm volatile("s_waitcnt vmcnt(8)" ::: "memory");  // tile0 k0 landed
  __builtin_amdgcn_s_barrier();
  asm volatile("" ::: "memory");

  f16x8 bf[4];
  for (int i = 0; i < 8; ++i) {       // 16 K-tiles, 2 per iteration
    const bool last = (i == 7);
#pragma unroll
    for (int ph = 0; ph < 8; ++ph) {
      const int bb = ph >> 2;         // buffer being computed
      const int ks = (ph >> 1) & 1;   // kstep (khalf)
      const int h  = ph & 1;          // token-row half of the wave's 128

      // ds-load register subtiles (phase h==0: 4B+4A, h==1: 4A)
      f16x8 af[4];
      if (h == 0) {
#pragma unroll
        for (int nn = 0; nn < 4; ++nn)
          bf[nn] = *(const f16x8*)&LB[bb * 16384 + ks * 8192 +
                                      (bslot + nn * 64) * 8];
      }
#pragma unroll
      for (int mm = 0; mm < 4; ++mm)
        af[mm] = *(const f16x8*)&LA[bb * 16384 + ks * 8192 +
                                    (aslot + (h * 4 + mm) * 64) * 8];

      // stage 1 half-tile (6-phase prefetch lead):
      // ph0:A(2i+1,k1) ph1:B(2i+1,k1) ph2:A(2i+2,k0) ph3:B(2i+2,k0)
      // ph4:A(2i+2,k1) ph5:B(2i+2,k1) ph6:A(2i+3,k0) ph7:B(2i+3,k0)
      {
        constexpr int toff[8] = {1, 1, 2, 2, 2, 2, 3, 3};
        constexpr int khv[8]  = {1, 1, 0, 0, 1, 1, 0, 0};
        if (!last || ph < 2) {
          const int tl = 2 * i + toff[ph];
          if (ph & 1) STAGE_B(tl, khv[ph]); else STAGE_A(tl, khv[ph]);
        }
      }

      __builtin_amdgcn_s_barrier();
      asm volatile("s_waitcnt lgkmcnt(0)" ::: "memory");

      __builtin_amdgcn_s_setprio(1);
#pragma unroll
      for (int mm = 0; mm < 4; ++mm)
#pragma unroll
        for (int nn = 0; nn < 4; ++nn)
          acc[h * 4 + mm][nn] = __builtin_amdgcn_mfma_f32_16x16x32_f16(
              af[mm], bf[nn], acc[h * 4 + mm][nn], 0, 0, 0);
      __builtin_amdgcn_s_setprio(0);

      // counted vmcnt at odd-phase ends only (never 0 until the tail)
      if (ph & 1) {
        if (!last) {
          asm volatile("s_waitcnt vmcnt(8)" ::: "memory");
        } else if (ph == 1) {
          asm volatile("s_waitcnt vmcnt(8)" ::: "memory");
        } else if (ph == 3) {
          asm volatile("s_waitcnt vmcnt(4)" ::: "memory");
        } else if (ph == 5) {
          asm volatile("s_waitcnt vmcnt(0)" ::: "memory");
        }  // ph==7 last: nothing left to wait for
      }
      __builtin_amdgcn_s_barrier();
      asm volatile("" ::: "memory");
    }
  }
#undef STAGE_A
#undef STAGE_B

  // ---------------- epilogues ----------------
  // C/D (16x16): channel col = l15, token row = oct4*4 + r
  if (EPI == 1) {
    float* out = (float*)o0v;
#pragma unroll
    for (int mm = 0; mm < 8; ++mm)
#pragma unroll
      for (int nn = 0; nn < 4; ++nn) {
        const int m = m0 + wc * 64 + nn * 16 + l15;
#pragma unroll
        for (int r = 0; r < 4; ++r) {
          const int n = n0 + wr * 128 + mm * 16 + oct4 * 4 + r;
          out[(size_t)n * 1024 + m] = acc[mm][nn][r];
        }
      }
    return;
  }

  if (m0 < 1024) {
    // forget gate a: sigmoid, stage 128x256 f16 chunks (stride 264)
    float bias[4];
#pragma unroll
    for (int nn = 0; nn < 4; ++nn)
      bias[nn] = gate_b[m0 + wc * 64 + nn * 16 + l15];
    f16* o0 = (f16*)o0v;
#pragma unroll
    for (int ck = 0; ck < 2; ++ck) {
      __builtin_amdgcn_s_barrier();
      asm volatile("" ::: "memory");
      if (wr == ck) {
#pragma unroll
        for (int mm = 0; mm < 8; ++mm)
#pragma unroll
          for (int nn = 0; nn < 4; ++nn) {
            const int ch = wc * 64 + nn * 16 + l15;
#pragma unroll
            for (int r = 0; r < 4; ++r) {
              const int nl = mm * 16 + oct4 * 4 + r;
              SH[nl * 264 + ch] = (f16)sigmoidf_(acc[mm][nn][r] + bias[nn]);
            }
          }
      }
      __builtin_amdgcn_s_barrier();
      asm volatile("" ::: "memory");
#pragma unroll
      for (int j = 0; j < 8; ++j) {
        int s = j * 512 + tid;
        int row = s >> 5, sl = s & 31;
        f16x8 vv = *(const f16x8*)&SH[row * 264 + sl * 8];
        *(f16x8*)(o0 + (size_t)(n0 + ck * 128 + row) * 1024 + m0 + sl * 8) =
            vv;
      }
    }
  } else {
    // bv = sigmoid(bg + bias) * v : even col bg, odd col v (same channel)
    const int c0 = (m0 - 1024) >> 1;
    float biasv[4];
#pragma unroll
    for (int nn = 0; nn < 4; ++nn) {
      const int ml = wc * 64 + nn * 16 + l15;
      biasv[nn] = gate_b[1024 + c0 + (ml >> 1)];
    }
    f16* o1 = (f16*)o1v;
#pragma unroll
    for (int ck = 0; ck < 2; ++ck) {
      __builtin_amdgcn_s_barrier();
      asm volatile("" ::: "memory");
      if (wr == ck) {
#pragma unroll
        for (int mm = 0; mm < 8; ++mm)
#pragma unroll
          for (int nn = 0; nn < 4; ++nn) {
            const int ml = wc * 64 + nn * 16 + l15;
#pragma unroll
            for (int r = 0; r < 4; ++r) {
              float val = acc[mm][nn][r];
              float pv = __shfl_xor(val, 1, 64);  // partner's value
              if (!(lane & 1)) {
                const int nl = mm * 16 + oct4 * 4 + r;
                SH[nl * 136 + (ml >> 1)] =
                    (f16)(sigmoidf_(val + biasv[nn]) * pv);
              }
            }
          }
      }
      __builtin_amdgcn_s_barrier();
      asm volatile("" ::: "memory");
#pragma unroll
      for (int j = 0; j < 4; ++j) {
        int s = j * 512 + tid;
        int row = s >> 4, sl = s & 15;
        f16x8 vv = *(const f16x8*)&SH[row * 136 + sl * 8];
        *(f16x8*)(o1 + (size_t)(n0 + ck * 128 + row) * 1024 + c0 + sl * 8) =
            vv;
      }
    }
  }
}

// ---------------- chunked scan: h_t = a_t*h_{t-1} + bv_t ----------------
// T=4096 = 128 chunks x 32; 2 channels/thread (f16x2).
__global__ __launch_bounds__(256) void scan_pass1(
    const f16x2* __restrict__ a, const f16x2* __restrict__ bv,
    float2* __restrict__ Ac, float2* __restrict__ Uc) {
  const int c2 = blockIdx.x * 256 + threadIdx.x;  // 0..511
  const int j = blockIdx.y;                       // 0..127
  const int b = blockIdx.z;
  const size_t base = ((size_t)(b * 4096 + j * 32)) * 512 + c2;
  float P0 = 1.f, P1 = 1.f, U0 = 0.f, U1 = 0.f;
#pragma unroll 8
  for (int t = 0; t < 32; ++t) {
    const size_t o = base + (size_t)t * 512;
    f16x2 at = a[o], bt = bv[o];
    float a0 = (float)at[0], a1 = (float)at[1];
    P0 *= a0; P1 *= a1;
    U0 = a0 * U0 + (float)bt[0];
    U1 = a1 * U1 + (float)bt[1];
  }
  const size_t o = ((size_t)(b * 128 + j)) * 512 + c2;
  Ac[o] = make_float2(P0, P1);
  Uc[o] = make_float2(U0, U1);
}

// segment-parallel inter-chunk scan: 64 channels x 4 segments of 32 chunks
__global__ __launch_bounds__(256) void scan_pass2(
    const float* __restrict__ Ac, const float* __restrict__ Uc,
    const float* __restrict__ h_prev, float* __restrict__ Hs,
    float* __restrict__ hlast) {
  __shared__ float SA[4][64], SU[4][64];
  const int tid = threadIdx.x;
  const int seg = tid >> 6;            // 0..3
  const int cl  = tid & 63;
  const int ch  = blockIdx.x * 64 + cl;  // 0..4095
  const int b = ch >> 10, c = ch & 1023;
  float A = 1.f, U = 0.f;
  for (int t = 0; t < 32; ++t) {
    const int j = seg * 32 + t;
    const size_t o = ((size_t)(b * 128 + j)) * 1024 + c;
    float av = Ac[o], uv = Uc[o];
    U = av * U + uv;
    A = av * A;
  }
  SA[seg][cl] = A;
  SU[seg][cl] = U;
  __syncthreads();
  float Ae = 1.f, Ue = 0.f;
  for (int s = 0; s < seg; ++s) {
    float av = SA[s][cl], uv = SU[s][cl];
    Ue = av * Ue + uv;
    Ae = av * Ae;
  }
  float H = Ae * h_prev[b * 1024 + c] + Ue;  // state entering my segment
  for (int t = 0; t < 32; ++t) {
    const int j = seg * 32 + t;
    const size_t o = ((size_t)(b * 128 + j)) * 1024 + c;
    Hs[o] = H;
    H = Ac[o] * H + Uc[o];
  }
  if (seg == 3) hlast[b * 1024 + c] = H;
}

__global__ __launch_bounds__(256) void scan_pass3(
    const f16x2* __restrict__ a, const f16x2* __restrict__ bv,
    const float2* __restrict__ Hs, f16x2* __restrict__ hb) {
  const int c2 = blockIdx.x * 256 + threadIdx.x;
  const int j = blockIdx.y;
  const int b = blockIdx.z;
  const size_t base = ((size_t)(b * 4096 + j * 32)) * 512 + c2;
  float2 H = Hs[((size_t)(b * 128 + j)) * 512 + c2];
  float h0 = H.x, h1 = H.y;
#pragma unroll 8
  for (int t = 0; t < 32; ++t) {
    const size_t o = base + (size_t)t * 512;
    f16x2 at = a[o], bt = bv[o];
    h0 = (float)at[0] * h0 + (float)bt[0];
    h1 = (float)at[1] * h1 + (float)bt[1];
    f16x2 hv; hv[0] = (f16)h0; hv[1] = (f16)h1;
    hb[o] = hv;
  }
}

extern "C" void kernel_launch(void* const* d_in, const int* in_sizes, int n_in,
                              void* d_out, int out_size, void* d_ws,
                              size_t ws_size, hipStream_t stream) {
  const float* x       = (const float*)d_in[0];
  const float* h_prev  = (const float*)d_in[1];
  const float* gate_w  = (const float*)d_in[2];
  const float* gate_b  = (const float*)d_in[3];
  const float* value_w = (const float*)d_in[4];
  const float* out_w   = (const float*)d_in[5];
  float* out = (float*)d_out;

  char* ws = (char*)d_ws;
  // ws layout (bytes), total ~115.3 MB:
  f16*   xh   = (f16*)(ws);                    // 33,554,432  x f16; reused as h
  f16*   wgv  = (f16*)(ws + 33554432);         //  6,291,456  packed weights
  f16*   owb  = (f16*)(ws + 39845888);         //  2,097,152  out_w f16
  f16*   abuf = (f16*)(ws + 41943040);         // 33,554,432  forget gate a
  f16*   bvb  = (f16*)(ws + 75497472);         // 33,554,432  bv = bg*v
  float* Ac   = (float*)(ws + 109051904);      //  2,097,152
  float* Uc   = (float*)(ws + 111149056);      //  2,097,152
  float* Hs   = (float*)(ws + 113246208);      //  2,097,152
  float* hlast = out + 16777216;

  // fused cast + weight packing
  cast_pack<<<10240, 256, 0, stream>>>(x, gate_w, value_w, out_w, xh, wgv,
                                       owb);

  // gates+values GEMM, fused sigmoid + bv epilogue (M=3072 -> 12 m-tiles)
  gemm256<0><<<dim3(768), 512, 0, stream>>>(xh, wgv, gate_b, abuf, bvb, 12);

  // chunked scan (128 chunks x 32)
  scan_pass1<<<dim3(2, 128, 4), 256, 0, stream>>>(
      (const f16x2*)abuf, (const f16x2*)bvb, (float2*)Ac, (float2*)Uc);
  scan_pass2<<<64, 256, 0, stream>>>(Ac, Uc, h_prev, Hs, hlast);
  scan_pass3<<<dim3(2, 128, 4), 256, 0, stream>>>(
      (const f16x2*)abuf, (const f16x2*)bvb, (const float2*)Hs, (f16x2*)xh);

  // output GEMM -> y fp32 (M=1024 -> 4 m-tiles)
  gemm256<1><<<dim3(256), 512, 0, stream>>>(xh, owb, nullptr, out, nullptr, 4);
}

// Round 2
// 361.726 us; speedup vs baseline: 1.0444x; 1.0444x over previous
//
#include <hip/hip_runtime.h>
#include <cstdint>
#include <cstddef>

// GLA layer: B=4, T=4096, D=1024, H=16, S=64
// fp16 pipeline, packed weights (a rows | interleaved bg/v rows).
// GEMMs = 256x256 8-phase template (16x16x32 MFMA, 8 waves, BK=64,
// double-buffered 128KB LDS, counted vmcnt(8), setprio, XCD swizzle).
// Fragment LDS reads are inline-asm ds_read_b128 (opaque to the compiler's
// waitcnt pass, so the counted-vmcnt pipeline survives; rule #18
// sched_barrier(0) after lgkmcnt(0)).
// GEMM1 epilogue: a = sigmoid(.), bv = sigmoid(.)*v (lane-pair shfl),
// LDS-staged f16x8 coalesced stores. Scan: 128 chunks x 32 steps,
// segment-parallel pass2. GEMM2 -> y fp32 direct stores.

typedef _Float16 f16;
typedef _Float16 f16x2 __attribute__((ext_vector_type(2)));
typedef _Float16 f16x8 __attribute__((ext_vector_type(8)));
typedef float    f32x4 __attribute__((ext_vector_type(4)));

__device__ __forceinline__ void gload_lds16(const void* g, void* l) {
  __builtin_amdgcn_global_load_lds(
      (const __attribute__((address_space(1))) void*)g,
      (__attribute__((address_space(3))) void*)l, 16, 0, 0);
}

__device__ __forceinline__ float sigmoidf_(float x) {
  return 1.0f / (1.0f + __expf(-x));
}

// ---------------- fused cast+pack fp32 -> fp16 ----------------
__global__ __launch_bounds__(256) void cast_pack(
    const float* __restrict__ x, const float* __restrict__ gw,
    const float* __restrict__ vw, const float* __restrict__ ow,
    f16* __restrict__ xh, f16* __restrict__ wgv, f16* __restrict__ owb) {
  const int XG = 2097152, GG = 262144, VG = 131072, OG = 131072;
  int id = blockIdx.x * 256 + threadIdx.x;
  const float* src;
  f16* dst;
  if (id < XG) {
    src = x + (size_t)id * 8;
    dst = xh + (size_t)id * 8;
  } else if (id < XG + GG) {
    int g = id - XG;
    int row = g >> 7, col = g & 127;
    int drow = (row < 1024) ? row : (1024 + 2 * (row - 1024));
    src = gw + ((size_t)row << 10) + col * 8;
    dst = wgv + ((size_t)drow << 10) + col * 8;
  } else if (id < XG + GG + VG) {
    int g = id - XG - GG;
    int row = g >> 7, col = g & 127;
    int drow = 1024 + 2 * row + 1;
    src = vw + ((size_t)row << 10) + col * 8;
    dst = wgv + ((size_t)drow << 10) + col * 8;
  } else if (id < XG + GG + VG + OG) {
    int g = id - XG - GG - VG;
    src = ow + (size_t)g * 8;
    dst = owb + (size_t)g * 8;
  } else {
    return;
  }
  float4 v0 = ((const float4*)src)[0], v1 = ((const float4*)src)[1];
  f16x8 o;
  o[0] = (f16)v0.x; o[1] = (f16)v0.y; o[2] = (f16)v0.z; o[3] = (f16)v0.w;
  o[4] = (f16)v1.x; o[5] = (f16)v1.y; o[6] = (f16)v1.z; o[7] = (f16)v1.w;
  *(f16x8*)dst = o;
}

// opaque LDS read: invisible to the compiler's vmcnt alias tracking.
#define DSREAD(dst, addr, off)                                        \
  asm volatile("ds_read_b128 %0, %1 offset:%2"                       \
               : "=v"(dst)                                            \
               : "v"(addr), "i"(off))

// ---- 256x256 8-phase fp16 MFMA GEMM: C[N,M] = A[N,K] * B[M,K]^T ----
// 8 waves (2 token-halves x 4 channel-quarters), per-wave 128x64 output.
// 16x16x32 MFMA. BK=64, staged as k-halves of 32. LDS 128KB (2 bufs).
// LDS layout per (buf,khalf): slot(row,oct) = row*4 + (oct ^ ((row>>1)&3)),
// 16B slots, achieved via pre-swizzled global source (gload_lds is linear).
template <int EPI>
__global__ __launch_bounds__(512, 2) void gemm256(
    const f16* __restrict__ A, const f16* __restrict__ Bw,
    const float* __restrict__ gate_b, void* __restrict__ o0v,
    void* __restrict__ o1v, int Mtiles) {
  constexpr int K = 1024;
  __shared__ __align__(16) f16 SH[65536];  // 128 KiB
  f16* LA = SH;          // 2 x (2 khalf x 8192 f16) = 32768 f16
  f16* LB = SH + 32768;

  const int tid  = threadIdx.x;
  const int lane = tid & 63;
  const int l15  = lane & 15;
  const int oct4 = lane >> 4;   // k-octet within a 32-wide kstep
  const int wid  = tid >> 6;
  const int wr   = wid >> 2;    // 0..1 token half
  const int wc   = wid & 3;     // 0..3 channel quarter

  // bijective XCD swizzle (grid % 8 == 0 for both launches)
  const int nwg = gridDim.x;
  const int bid = blockIdx.x;
  const int swz = (bid & 7) * (nwg >> 3) + (bid >> 3);
  const int m0 = (swz % Mtiles) * 256;
  const int n0 = (swz / Mtiles) * 256;

  // staging addresses: thread covers (row=tid>>2, physOct=tid&3), j=1 -> row+128
  const int srow = tid >> 2;
  const int soct = (tid & 3) ^ ((srow >> 1) & 3);  // swizzled source octet
  const f16* Ag = A  + (size_t)(n0 + srow) * K + soct * 8;
  const f16* Bg = Bw + (size_t)(m0 + srow) * K + soct * 8;
  f16* Al = LA + tid * 8;  // + buf*16384 + khalf*8192 ; j=1: +4096
  f16* Bl = LB + tid * 8;

  // fragment read byte addresses (swz indep. of mm/nn: +16 rows = +1024 B)
  const int fswz  = oct4 ^ ((l15 >> 1) & 3);
  const unsigned shbase = (unsigned)(uintptr_t)(&SH[0]);
  const int aaddr = (int)shbase + ((wr * 128 + l15) * 4 + fswz) * 16;
  const int baddr = (int)shbase + 65536 + ((wc * 64 + l15) * 4 + fswz) * 16;

  f32x4 acc[8][4];
#pragma unroll
  for (int mm = 0; mm < 8; ++mm)
#pragma unroll
    for (int nn = 0; nn < 4; ++nn)
#pragma unroll
      for (int e = 0; e < 4; ++e) acc[mm][nn][e] = 0.f;

#define STAGE_A(tl, kh)                                          \
  do {                                                           \
    const f16* s_ = Ag + (tl) * 64 + (kh) * 32;                  \
    f16* d_ = Al + ((tl) & 1) * 16384 + (kh) * 8192;             \
    gload_lds16(s_, d_);                                         \
    gload_lds16(s_ + 128 * K, d_ + 4096);                        \
  } while (0)
#define STAGE_B(tl, kh)                                          \
  do {                                                           \
    const f16* s_ = Bg + (tl) * 64 + (kh) * 32;                  \
    f16* d_ = Bl + ((tl) & 1) * 16384 + (kh) * 8192;             \
    gload_lds16(s_, d_);                                         \
    gload_lds16(s_ + 128 * K, d_ + 4096);                        \
  } while (0)

  // prologue: tile0 k0, tile0 k1, tile1 k0 (12 loads in flight)
  STAGE_A(0, 0); STAGE_B(0, 0);
  STAGE_A(0, 1); STAGE_B(0, 1);
  STAGE_A(1, 0); STAGE_B(1, 0);
  asm volatile("s_waitcnt vmcnt(8)" ::: "memory");  // tile0 k0 landed
  __builtin_amdgcn_s_barrier();
  asm volatile("" ::: "memory");

  f16x8 bf[4];
  for (int i = 0; i < 8; ++i) {       // 16 K-tiles, 2 per iteration
    const bool last = (i == 7);
#pragma unroll
    for (int ph = 0; ph < 8; ++ph) {
      constexpr int OFFB[8] = {0,     0,     16384, 16384,
                               32768, 32768, 49152, 49152};  // bb*32768+ks*16384
      const int bb = ph >> 2;         // buffer being computed
      const int h  = ph & 1;          // token-row half of the wave's 128
      const int obase = OFFB[ph];

      // opaque ds_read_b128 fragment loads (phase h==0: 4B+4A, h==1: 4A)
      f16x8 af[4];
      if (h == 0) {
        switch (obase) {
          case 0:
            DSREAD(bf[0], baddr, 0);     DSREAD(bf[1], baddr, 1024);
            DSREAD(bf[2], baddr, 2048);  DSREAD(bf[3], baddr, 3072);
            break;
          case 16384:
            DSREAD(bf[0], baddr, 16384); DSREAD(bf[1], baddr, 17408);
            DSREAD(bf[2], baddr, 18432); DSREAD(bf[3], baddr, 19456);
            break;
          case 32768:
            DSREAD(bf[0], baddr, 32768); DSREAD(bf[1], baddr, 33792);
            DSREAD(bf[2], baddr, 34816); DSREAD(bf[3], baddr, 35840);
            break;
          default:
            DSREAD(bf[0], baddr, 49152); DSREAD(bf[1], baddr, 50176);
            DSREAD(bf[2], baddr, 51200); DSREAD(bf[3], baddr, 52224);
            break;
        }
      }
      {
        const int ab = obase + h * 4096;
        switch (ab) {
          case 0:
            DSREAD(af[0], aaddr, 0);     DSREAD(af[1], aaddr, 1024);
            DSREAD(af[2], aaddr, 2048);  DSREAD(af[3], aaddr, 3072);
            break;
          case 4096:
            DSREAD(af[0], aaddr, 4096);  DSREAD(af[1], aaddr, 5120);
            DSREAD(af[2], aaddr, 6144);  DSREAD(af[3], aaddr, 7168);
            break;
          case 16384:
            DSREAD(af[0], aaddr, 16384); DSREAD(af[1], aaddr, 17408);
            DSREAD(af[2], aaddr, 18432); DSREAD(af[3], aaddr, 19456);
            break;
          case 20480:
            DSREAD(af[0], aaddr, 20480); DSREAD(af[1], aaddr, 21504);
            DSREAD(af[2], aaddr, 22528); DSREAD(af[3], aaddr, 23552);
            break;
          case 32768:
            DSREAD(af[0], aaddr, 32768); DSREAD(af[1], aaddr, 33792);
            DSREAD(af[2], aaddr, 34816); DSREAD(af[3], aaddr, 35840);
            break;
          case 36864:
            DSREAD(af[0], aaddr, 36864); DSREAD(af[1], aaddr, 37888);
            DSREAD(af[2], aaddr, 38912); DSREAD(af[3], aaddr, 39936);
            break;
          case 49152:
            DSREAD(af[0], aaddr, 49152); DSREAD(af[1], aaddr, 50176);
            DSREAD(af[2], aaddr, 51200); DSREAD(af[3], aaddr, 52224);
            break;
          default:
            DSREAD(af[0], aaddr, 53248); DSREAD(af[1], aaddr, 54272);
            DSREAD(af[2], aaddr, 55296); DSREAD(af[3], aaddr, 56320);
            break;
        }
      }

      // stage 1 half-tile (6-phase prefetch lead):
      // ph0:A(2i+1,k1) ph1:B(2i+1,k1) ph2:A(2i+2,k0) ph3:B(2i+2,k0)
      // ph4:A(2i+2,k1) ph5:B(2i+2,k1) ph6:A(2i+3,k0) ph7:B(2i+3,k0)
      {
        constexpr int toff[8] = {1, 1, 2, 2, 2, 2, 3, 3};
        constexpr int khv[8]  = {1, 1, 0, 0, 1, 1, 0, 0};
        if (!last || ph < 2) {
          const int tl = 2 * i + toff[ph];
          if (ph & 1) STAGE_B(tl, khv[ph]); else STAGE_A(tl, khv[ph]);
        }
      }

      __builtin_amdgcn_s_barrier();
      asm volatile("s_waitcnt lgkmcnt(0)" ::: "memory");
      __builtin_amdgcn_sched_barrier(0);  // rule #18: pin MFMA below the wait

      __builtin_amdgcn_s_setprio(1);
#pragma unroll
      for (int mm = 0; mm < 4; ++mm)
#pragma unroll
        for (int nn = 0; nn < 4; ++nn)
          acc[h * 4 + mm][nn] = __builtin_amdgcn_mfma_f32_16x16x32_f16(
              af[mm], bf[nn], acc[h * 4 + mm][nn], 0, 0, 0);
      __builtin_amdgcn_s_setprio(0);

      // counted vmcnt at odd-phase ends only (never 0 until the tail)
      if (ph & 1) {
        if (!last) {
          asm volatile("s_waitcnt vmcnt(8)" ::: "memory");
        } else if (ph == 1) {
          asm volatile("s_waitcnt vmcnt(8)" ::: "memory");
        } else if (ph == 3) {
          asm volatile("s_waitcnt vmcnt(4)" ::: "memory");
        } else if (ph == 5) {
          asm volatile("s_waitcnt vmcnt(0)" ::: "memory");
        }  // ph==7 last: nothing left to wait for
      }
      __builtin_amdgcn_s_barrier();
      asm volatile("" ::: "memory");
    }
  }
#undef STAGE_A
#undef STAGE_B

  // ---------------- epilogues ----------------
  // C/D (16x16): channel col = l15, token row = oct4*4 + r
  if (EPI == 1) {
    float* out = (float*)o0v;
#pragma unroll
    for (int mm = 0; mm < 8; ++mm)
#pragma unroll
      for (int nn = 0; nn < 4; ++nn) {
        const int m = m0 + wc * 64 + nn * 16 + l15;
#pragma unroll
        for (int r = 0; r < 4; ++r) {
          const int n = n0 + wr * 128 + mm * 16 + oct4 * 4 + r;
          out[(size_t)n * 1024 + m] = acc[mm][nn][r];
        }
      }
    return;
  }

  if (m0 < 1024) {
    // forget gate a: sigmoid, stage 128x256 f16 chunks (stride 264)
    float bias[4];
#pragma unroll
    for (int nn = 0; nn < 4; ++nn)
      bias[nn] = gate_b[m0 + wc * 64 + nn * 16 + l15];
    f16* o0 = (f16*)o0v;
#pragma unroll
    for (int ck = 0; ck < 2; ++ck) {
      __builtin_amdgcn_s_barrier();
      asm volatile("" ::: "memory");
      if (wr == ck) {
#pragma unroll
        for (int mm = 0; mm < 8; ++mm)
#pragma unroll
          for (int nn = 0; nn < 4; ++nn) {
            const int ch = wc * 64 + nn * 16 + l15;
#pragma unroll
            for (int r = 0; r < 4; ++r) {
              const int nl = mm * 16 + oct4 * 4 + r;
              SH[nl * 264 + ch] = (f16)sigmoidf_(acc[mm][nn][r] + bias[nn]);
            }
          }
      }
      __builtin_amdgcn_s_barrier();
      asm volatile("" ::: "memory");
#pragma unroll
      for (int j = 0; j < 8; ++j) {
        int s = j * 512 + tid;
        int row = s >> 5, sl = s & 31;
        f16x8 vv = *(const f16x8*)&SH[row * 264 + sl * 8];
        *(f16x8*)(o0 + (size_t)(n0 + ck * 128 + row) * 1024 + m0 + sl * 8) =
            vv;
      }
    }
  } else {
    // bv = sigmoid(bg + bias) * v : even col bg, odd col v (same channel)
    const int c0 = (m0 - 1024) >> 1;
    float biasv[4];
#pragma unroll
    for (int nn = 0; nn < 4; ++nn) {
      const int ml = wc * 64 + nn * 16 + l15;
      biasv[nn] = gate_b[1024 + c0 + (ml >> 1)];
    }
    f16* o1 = (f16*)o1v;
#pragma unroll
    for (int ck = 0; ck < 2; ++ck) {
      __builtin_amdgcn_s_barrier();
      asm volatile("" ::: "memory");
      if (wr == ck) {
#pragma unroll
        for (int mm = 0; mm < 8; ++mm)
#pragma unroll
          for (int nn = 0; nn < 4; ++nn) {
            const int ml = wc * 64 + nn * 16 + l15;
#pragma unroll
            for (int r = 0; r < 4; ++r) {
              float val = acc[mm][nn][r];
              float pv = __shfl_xor(val, 1, 64);  // partner's value
              if (!(lane & 1)) {
                const int nl = mm * 16 + oct4 * 4 + r;
                SH[nl * 136 + (ml >> 1)] =
                    (f16)(sigmoidf_(val + biasv[nn]) * pv);
              }
            }
          }
      }
      __builtin_amdgcn_s_barrier();
      asm volatile("" ::: "memory");
#pragma unroll
      for (int j = 0; j < 4; ++j) {
        int s = j * 512 + tid;
        int row = s >> 4, sl = s & 15;
        f16x8 vv = *(const f16x8*)&SH[row * 136 + sl * 8];
        *(f16x8*)(o1 + (size_t)(n0 + ck * 128 + row) * 1024 + c0 + sl * 8) =
            vv;
      }
    }
  }
}

// ---------------- chunked scan: h_t = a_t*h_{t-1} + bv_t ----------------
// T=4096 = 128 chunks x 32; 2 channels/thread (f16x2).
__global__ __launch_bounds__(256) void scan_pass1(
    const f16x2* __restrict__ a, const f16x2* __restrict__ bv,
    float2* __restrict__ Ac, float2* __restrict__ Uc) {
  const int c2 = blockIdx.x * 256 + threadIdx.x;  // 0..511
  const int j = blockIdx.y;                       // 0..127
  const int b = blockIdx.z;
  const size_t base = ((size_t)(b * 4096 + j * 32)) * 512 + c2;
  float P0 = 1.f, P1 = 1.f, U0 = 0.f, U1 = 0.f;
#pragma unroll 8
  for (int t = 0; t < 32; ++t) {
    const size_t o = base + (size_t)t * 512;
    f16x2 at = a[o], bt = bv[o];
    float a0 = (float)at[0], a1 = (float)at[1];
    P0 *= a0; P1 *= a1;
    U0 = a0 * U0 + (float)bt[0];
    U1 = a1 * U1 + (float)bt[1];
  }
  const size_t o = ((size_t)(b * 128 + j)) * 512 + c2;
  Ac[o] = make_float2(P0, P1);
  Uc[o] = make_float2(U0, U1);
}

// segment-parallel inter-chunk scan: 64 channels x 4 segments of 32 chunks
__global__ __launch_bounds__(256) void scan_pass2(
    const float* __restrict__ Ac, const float* __restrict__ Uc,
    const float* __restrict__ h_prev, float* __restrict__ Hs,
    float* __restrict__ hlast) {
  __shared__ float SA[4][64], SU[4][64];
  const int tid = threadIdx.x;
  const int seg = tid >> 6;            // 0..3
  const int cl  = tid & 63;
  const int ch  = blockIdx.x * 64 + cl;  // 0..4095
  const int b = ch >> 10, c = ch & 1023;
  float A = 1.f, U = 0.f;
  for (int t = 0; t < 32; ++t) {
    const int j = seg * 32 + t;
    const size_t o = ((size_t)(b * 128 + j)) * 1024 + c;
    float av = Ac[o], uv = Uc[o];
    U = av * U + uv;
    A = av * A;
  }
  SA[seg][cl] = A;
  SU[seg][cl] = U;
  __syncthreads();
  float Ae = 1.f, Ue = 0.f;
  for (int s = 0; s < seg; ++s) {
    float av = SA[s][cl], uv = SU[s][cl];
    Ue = av * Ue + uv;
    Ae = av * Ae;
  }
  float H = Ae * h_prev[b * 1024 + c] + Ue;  // state entering my segment
  for (int t = 0; t < 32; ++t) {
    const int j = seg * 32 + t;
    const size_t o = ((size_t)(b * 128 + j)) * 1024 + c;
    Hs[o] = H;
    H = Ac[o] * H + Uc[o];
  }
  if (seg == 3) hlast[b * 1024 + c] = H;
}

__global__ __launch_bounds__(256) void scan_pass3(
    const f16x2* __restrict__ a, const f16x2* __restrict__ bv,
    const float2* __restrict__ Hs, f16x2* __restrict__ hb) {
  const int c2 = blockIdx.x * 256 + threadIdx.x;
  const int j = blockIdx.y;
  const int b = blockIdx.z;
  const size_t base = ((size_t)(b * 4096 + j * 32)) * 512 + c2;
  float2 H = Hs[((size_t)(b * 128 + j)) * 512 + c2];
  float h0 = H.x, h1 = H.y;
#pragma unroll 8
  for (int t = 0; t < 32; ++t) {
    const size_t o = base + (size_t)t * 512;
    f16x2 at = a[o], bt = bv[o];
    h0 = (float)at[0] * h0 + (float)bt[0];
    h1 = (float)at[1] * h1 + (float)bt[1];
    f16x2 hv; hv[0] = (f16)h0; hv[1] = (f16)h1;
    hb[o] = hv;
  }
}

extern "C" void kernel_launch(void* const* d_in, const int* in_sizes, int n_in,
                              void* d_out, int out_size, void* d_ws,
                              size_t ws_size, hipStream_t stream) {
  const float* x       = (const float*)d_in[0];
  const float* h_prev  = (const float*)d_in[1];
  const float* gate_w  = (const float*)d_in[2];
  const float* gate_b  = (const float*)d_in[3];
  const float* value_w = (const float*)d_in[4];
  const float* out_w   = (const float*)d_in[5];
  float* out = (float*)d_out;

  char* ws = (char*)d_ws;
  // ws layout (bytes), total ~115.3 MB:
  f16*   xh   = (f16*)(ws);                    // 33,554,432  x f16; reused as h
  f16*   wgv  = (f16*)(ws + 33554432);         //  6,291,456  packed weights
  f16*   owb  = (f16*)(ws + 39845888);         //  2,097,152  out_w f16
  f16*   abuf = (f16*)(ws + 41943040);         // 33,554,432  forget gate a
  f16*   bvb  = (f16*)(ws + 75497472);         // 33,554,432  bv = bg*v
  float* Ac   = (float*)(ws + 109051904);      //  2,097,152
  float* Uc   = (float*)(ws + 111149056);      //  2,097,152
  float* Hs   = (float*)(ws + 113246208);      //  2,097,152
  float* hlast = out + 16777216;

  // fused cast + weight packing
  cast_pack<<<10240, 256, 0, stream>>>(x, gate_w, value_w, out_w, xh, wgv,
                                       owb);

  // gates+values GEMM, fused sigmoid + bv epilogue (M=3072 -> 12 m-tiles)
  gemm256<0><<<dim3(768), 512, 0, stream>>>(xh, wgv, gate_b, abuf, bvb, 12);

  // chunked scan (128 chunks x 32)
  scan_pass1<<<dim3(2, 128, 4), 256, 0, stream>>>(
      (const f16x2*)abuf, (const f16x2*)bvb, (float2*)Ac, (float2*)Uc);
  scan_pass2<<<64, 256, 0, stream>>>(Ac, Uc, h_prev, Hs, hlast);
  scan_pass3<<<dim3(2, 128, 4), 256, 0, stream>>>(
      (const f16x2*)abuf, (const f16x2*)bvb, (const float2*)Hs, (f16x2*)xh);

  // output GEMM -> y fp32 (M=1024 -> 4 m-tiles)
  gemm256<1><<<dim3(256), 512, 0, stream>>>(xh, owb, nullptr, out, nullptr, 4);
}

// Round 3
// 354.501 us; speedup vs baseline: 1.0657x; 1.0204x over previous
//
#include <hip/hip_runtime.h>
#include <cstdint>
#include <cstddef>

// GLA layer: B=4, T=4096, D=1024, H=16, S=64
// fp16 pipeline, packed weights (a rows | interleaved bg/v rows).
// GEMMs = 256x256 tile, 8 waves, 16x16x32 MFMA. K-loop = 32 merged phases
// (one per K-step-32): 12 ds_read + 4 global_load_lds + 32 MFMA with
// COUNTED lgkmcnt(7/4/0) interleave (LDS drain overlaps MFMA), vmcnt(4)
// never-zero, ONE barrier per phase. LDS = 4-region K-step ring x (A,B),
// 128 KB, XOR-swizzled via pre-swizzled global source. XCD swizzle.
// GEMM1 epilogue: a = sigmoid(.), bv = sigmoid(.)*v (lane-pair shfl),
// LDS-staged f16x8 coalesced stores. Scan: 128 chunks x 32 steps,
// segment-parallel pass2. GEMM2 -> y fp32 direct stores.

typedef _Float16 f16;
typedef _Float16 f16x2 __attribute__((ext_vector_type(2)));
typedef _Float16 f16x8 __attribute__((ext_vector_type(8)));
typedef float    f32x4 __attribute__((ext_vector_type(4)));

__device__ __forceinline__ void gload_lds16(const void* g, void* l) {
  __builtin_amdgcn_global_load_lds(
      (const __attribute__((address_space(1))) void*)g,
      (__attribute__((address_space(3))) void*)l, 16, 0, 0);
}

__device__ __forceinline__ float sigmoidf_(float x) {
  return 1.0f / (1.0f + __expf(-x));
}

// ---------------- fused cast+pack fp32 -> fp16 ----------------
__global__ __launch_bounds__(256) void cast_pack(
    const float* __restrict__ x, const float* __restrict__ gw,
    const float* __restrict__ vw, const float* __restrict__ ow,
    f16* __restrict__ xh, f16* __restrict__ wgv, f16* __restrict__ owb) {
  const int XG = 2097152, GG = 262144, VG = 131072, OG = 131072;
  int id = blockIdx.x * 256 + threadIdx.x;
  const float* src;
  f16* dst;
  if (id < XG) {
    src = x + (size_t)id * 8;
    dst = xh + (size_t)id * 8;
  } else if (id < XG + GG) {
    int g = id - XG;
    int row = g >> 7, col = g & 127;
    int drow = (row < 1024) ? row : (1024 + 2 * (row - 1024));
    src = gw + ((size_t)row << 10) + col * 8;
    dst = wgv + ((size_t)drow << 10) + col * 8;
  } else if (id < XG + GG + VG) {
    int g = id - XG - GG;
    int row = g >> 7, col = g & 127;
    int drow = 1024 + 2 * row + 1;
    src = vw + ((size_t)row << 10) + col * 8;
    dst = wgv + ((size_t)drow << 10) + col * 8;
  } else if (id < XG + GG + VG + OG) {
    int g = id - XG - GG - VG;
    src = ow + (size_t)g * 8;
    dst = owb + (size_t)g * 8;
  } else {
    return;
  }
  float4 v0 = ((const float4*)src)[0], v1 = ((const float4*)src)[1];
  f16x8 o;
  o[0] = (f16)v0.x; o[1] = (f16)v0.y; o[2] = (f16)v0.z; o[3] = (f16)v0.w;
  o[4] = (f16)v1.x; o[5] = (f16)v1.y; o[6] = (f16)v1.z; o[7] = (f16)v1.w;
  *(f16x8*)dst = o;
}

// opaque LDS read: invisible to the compiler's waitcnt alias tracking.
#define DSREAD(dst, addr, off)                                        \
  asm volatile("ds_read_b128 %0, %1 offset:%2"                       \
               : "=v"(dst)                                            \
               : "v"(addr), "i"(off))

#define WAIT_LGKM(n)                                                  \
  asm volatile("s_waitcnt lgkmcnt(" #n ")" ::: "memory");             \
  __builtin_amdgcn_sched_barrier(0)

// ---- 256x256 fp16 MFMA GEMM: C[N,M] = A[N,K] * B[M,K]^T ----
// 8 waves (2 token-halves x 4 channel-quarters), per-wave 128x64 output.
template <int EPI>
__global__ __launch_bounds__(512, 2) void gemm256(
    const f16* __restrict__ A, const f16* __restrict__ Bw,
    const float* __restrict__ gate_b, void* __restrict__ o0v,
    void* __restrict__ o1v, int Mtiles) {
  constexpr int K = 1024;
  __shared__ __align__(16) f16 SH[65536];  // 128 KiB
  f16* LA = SH;          // 4 regions x 8192 f16 (16 KB each)
  f16* LB = SH + 32768;

  const int tid  = threadIdx.x;
  const int lane = tid & 63;
  const int l15  = lane & 15;
  const int oct4 = lane >> 4;   // k-octet within a 32-wide kstep
  const int wid  = tid >> 6;
  const int wr   = wid >> 2;    // 0..1 token half
  const int wc   = wid & 3;     // 0..3 channel quarter

  // bijective XCD swizzle (grid % 8 == 0 for both launches)
  const int nwg = gridDim.x;
  const int bid = blockIdx.x;
  const int swz = (bid & 7) * (nwg >> 3) + (bid >> 3);
  const int m0 = (swz % Mtiles) * 256;
  const int n0 = (swz / Mtiles) * 256;

  // staging: thread covers (row=tid>>2, physOct=(tid&3)^((row>>1)&3))
  const int srow = tid >> 2;
  const int soct = (tid & 3) ^ ((srow >> 1) & 3);
  const f16* Ag = A  + (size_t)(n0 + srow) * K + soct * 8;
  const f16* Bg = Bw + (size_t)(m0 + srow) * K + soct * 8;
  f16* Al = LA + tid * 8;
  f16* Bl = LB + tid * 8;

  // fragment read byte addresses (fswz indep. of mm/nn: +16 rows = +1024 B)
  const int fswz  = oct4 ^ ((l15 >> 1) & 3);
  const unsigned shbase = (unsigned)(uintptr_t)(&SH[0]);
  const int aaddr = (int)shbase + ((wr * 128 + l15) * 4 + fswz) * 16;
  const int baddr = (int)shbase + 65536 + ((wc * 64 + l15) * 4 + fswz) * 16;

  f32x4 acc[8][4];
#pragma unroll
  for (int mm = 0; mm < 8; ++mm)
#pragma unroll
    for (int nn = 0; nn < 4; ++nn)
#pragma unroll
      for (int e = 0; e < 4; ++e) acc[mm][nn][e] = 0.f;

  // stage K-step kt's A+B half-panels into LDS region kt&3 (4 gloads/thread)
#define STAGE_AB(kt)                                                  \
  do {                                                                \
    const f16* sa_ = Ag + (kt) * 32;                                  \
    const f16* sb_ = Bg + (kt) * 32;                                  \
    f16* da_ = Al + ((kt) & 3) * 8192;                                \
    f16* db_ = Bl + ((kt) & 3) * 8192;                                \
    gload_lds16(sa_, da_);                                            \
    gload_lds16(sa_ + 128 * K, da_ + 4096);                           \
    gload_lds16(sb_, db_);                                            \
    gload_lds16(sb_ + 128 * K, db_ + 4096);                           \
  } while (0)

  // prologue: regions 0,1 (8 gloads); wait region 0
  STAGE_AB(0);
  STAGE_AB(1);
  asm volatile("s_waitcnt vmcnt(4)" ::: "memory");
  __builtin_amdgcn_s_barrier();
  asm volatile("" ::: "memory");

#pragma unroll
  for (int kt = 0; kt < 32; ++kt) {
    const int roff = (kt & 3) * 16384;
    const int aP = aaddr + roff;
    const int bP = baddr + roff;
    f16x8 af[8], bf[4];
    // issue order matters for the counted lgkm waits below
    DSREAD(bf[0], bP, 0);    DSREAD(bf[1], bP, 1024);
    DSREAD(bf[2], bP, 2048); DSREAD(bf[3], bP, 3072);
    DSREAD(af[0], aP, 0);    DSREAD(af[1], aP, 1024);
    DSREAD(af[2], aP, 2048); DSREAD(af[3], aP, 3072);
    DSREAD(af[4], aP, 4096); DSREAD(af[5], aP, 5120);
    DSREAD(af[6], aP, 6144); DSREAD(af[7], aP, 7168);

    if (kt < 30) STAGE_AB(kt + 2);  // 4 gloads (vmcnt +4)

    __builtin_amdgcn_s_setprio(1);
    // bf[0..3]+af[0] ready -> mm=0 while af[1..7] drain under the MFMAs
    WAIT_LGKM(7);
#pragma unroll
    for (int nn = 0; nn < 4; ++nn)
      acc[0][nn] = __builtin_amdgcn_mfma_f32_16x16x32_f16(
          af[0], bf[nn], acc[0][nn], 0, 0, 0);
    WAIT_LGKM(4);
#pragma unroll
    for (int mm = 1; mm < 4; ++mm)
#pragma unroll
      for (int nn = 0; nn < 4; ++nn)
        acc[mm][nn] = __builtin_amdgcn_mfma_f32_16x16x32_f16(
            af[mm], bf[nn], acc[mm][nn], 0, 0, 0);
    WAIT_LGKM(0);
#pragma unroll
    for (int mm = 4; mm < 8; ++mm)
#pragma unroll
      for (int nn = 0; nn < 4; ++nn)
        acc[mm][nn] = __builtin_amdgcn_mfma_f32_16x16x32_f16(
            af[mm], bf[nn], acc[mm][nn], 0, 0, 0);
    __builtin_amdgcn_s_setprio(0);

    // region kt+1 must be landed before the barrier releases phase kt+1
    if (kt < 30) {
      asm volatile("s_waitcnt vmcnt(4)" ::: "memory");
    } else if (kt == 30) {
      asm volatile("s_waitcnt vmcnt(0)" ::: "memory");
    }
    __builtin_amdgcn_s_barrier();
    asm volatile("" ::: "memory");
  }
#undef STAGE_AB

  // ---------------- epilogues ----------------
  // C/D (16x16): channel col = l15, token row = oct4*4 + r
  if (EPI == 1) {
    float* out = (float*)o0v;
#pragma unroll
    for (int mm = 0; mm < 8; ++mm)
#pragma unroll
      for (int nn = 0; nn < 4; ++nn) {
        const int m = m0 + wc * 64 + nn * 16 + l15;
#pragma unroll
        for (int r = 0; r < 4; ++r) {
          const int n = n0 + wr * 128 + mm * 16 + oct4 * 4 + r;
          out[(size_t)n * 1024 + m] = acc[mm][nn][r];
        }
      }
    return;
  }

  if (m0 < 1024) {
    // forget gate a: sigmoid, stage 128x256 f16 chunks (stride 264)
    float bias[4];
#pragma unroll
    for (int nn = 0; nn < 4; ++nn)
      bias[nn] = gate_b[m0 + wc * 64 + nn * 16 + l15];
    f16* o0 = (f16*)o0v;
#pragma unroll
    for (int ck = 0; ck < 2; ++ck) {
      __builtin_amdgcn_s_barrier();
      asm volatile("" ::: "memory");
      if (wr == ck) {
#pragma unroll
        for (int mm = 0; mm < 8; ++mm)
#pragma unroll
          for (int nn = 0; nn < 4; ++nn) {
            const int ch = wc * 64 + nn * 16 + l15;
#pragma unroll
            for (int r = 0; r < 4; ++r) {
              const int nl = mm * 16 + oct4 * 4 + r;
              SH[nl * 264 + ch] = (f16)sigmoidf_(acc[mm][nn][r] + bias[nn]);
            }
          }
      }
      __builtin_amdgcn_s_barrier();
      asm volatile("" ::: "memory");
#pragma unroll
      for (int j = 0; j < 8; ++j) {
        int s = j * 512 + tid;
        int row = s >> 5, sl = s & 31;
        f16x8 vv = *(const f16x8*)&SH[row * 264 + sl * 8];
        *(f16x8*)(o0 + (size_t)(n0 + ck * 128 + row) * 1024 + m0 + sl * 8) =
            vv;
      }
    }
  } else {
    // bv = sigmoid(bg + bias) * v : even col bg, odd col v (same channel)
    const int c0 = (m0 - 1024) >> 1;
    float biasv[4];
#pragma unroll
    for (int nn = 0; nn < 4; ++nn) {
      const int ml = wc * 64 + nn * 16 + l15;
      biasv[nn] = gate_b[1024 + c0 + (ml >> 1)];
    }
    f16* o1 = (f16*)o1v;
#pragma unroll
    for (int ck = 0; ck < 2; ++ck) {
      __builtin_amdgcn_s_barrier();
      asm volatile("" ::: "memory");
      if (wr == ck) {
#pragma unroll
        for (int mm = 0; mm < 8; ++mm)
#pragma unroll
          for (int nn = 0; nn < 4; ++nn) {
            const int ml = wc * 64 + nn * 16 + l15;
#pragma unroll
            for (int r = 0; r < 4; ++r) {
              float val = acc[mm][nn][r];
              float pv = __shfl_xor(val, 1, 64);  // partner's value
              if (!(lane & 1)) {
                const int nl = mm * 16 + oct4 * 4 + r;
                SH[nl * 136 + (ml >> 1)] =
                    (f16)(sigmoidf_(val + biasv[nn]) * pv);
              }
            }
          }
      }
      __builtin_amdgcn_s_barrier();
      asm volatile("" ::: "memory");
#pragma unroll
      for (int j = 0; j < 4; ++j) {
        int s = j * 512 + tid;
        int row = s >> 4, sl = s & 15;
        f16x8 vv = *(const f16x8*)&SH[row * 136 + sl * 8];
        *(f16x8*)(o1 + (size_t)(n0 + ck * 128 + row) * 1024 + c0 + sl * 8) =
            vv;
      }
    }
  }
}

// ---------------- chunked scan: h_t = a_t*h_{t-1} + bv_t ----------------
// T=4096 = 128 chunks x 32; 2 channels/thread (f16x2).
__global__ __launch_bounds__(256) void scan_pass1(
    const f16x2* __restrict__ a, const f16x2* __restrict__ bv,
    float2* __restrict__ Ac, float2* __restrict__ Uc) {
  const int c2 = blockIdx.x * 256 + threadIdx.x;  // 0..511
  const int j = blockIdx.y;                       // 0..127
  const int b = blockIdx.z;
  const size_t base = ((size_t)(b * 4096 + j * 32)) * 512 + c2;
  float P0 = 1.f, P1 = 1.f, U0 = 0.f, U1 = 0.f;
#pragma unroll 8
  for (int t = 0; t < 32; ++t) {
    const size_t o = base + (size_t)t * 512;
    f16x2 at = a[o], bt = bv[o];
    float a0 = (float)at[0], a1 = (float)at[1];
    P0 *= a0; P1 *= a1;
    U0 = a0 * U0 + (float)bt[0];
    U1 = a1 * U1 + (float)bt[1];
  }
  const size_t o = ((size_t)(b * 128 + j)) * 512 + c2;
  Ac[o] = make_float2(P0, P1);
  Uc[o] = make_float2(U0, U1);
}

// segment-parallel inter-chunk scan: 64 channels x 4 segments of 32 chunks
__global__ __launch_bounds__(256) void scan_pass2(
    const float* __restrict__ Ac, const float* __restrict__ Uc,
    const float* __restrict__ h_prev, float* __restrict__ Hs,
    float* __restrict__ hlast) {
  __shared__ float SA[4][64], SU[4][64];
  const int tid = threadIdx.x;
  const int seg = tid >> 6;            // 0..3
  const int cl  = tid & 63;
  const int ch  = blockIdx.x * 64 + cl;  // 0..4095
  const int b = ch >> 10, c = ch & 1023;
  float A = 1.f, U = 0.f;
  for (int t = 0; t < 32; ++t) {
    const int j = seg * 32 + t;
    const size_t o = ((size_t)(b * 128 + j)) * 1024 + c;
    float av = Ac[o], uv = Uc[o];
    U = av * U + uv;
    A = av * A;
  }
  SA[seg][cl] = A;
  SU[seg][cl] = U;
  __syncthreads();
  float Ae = 1.f, Ue = 0.f;
  for (int s = 0; s < seg; ++s) {
    float av = SA[s][cl], uv = SU[s][cl];
    Ue = av * Ue + uv;
    Ae = av * Ae;
  }
  float H = Ae * h_prev[b * 1024 + c] + Ue;  // state entering my segment
  for (int t = 0; t < 32; ++t) {
    const int j = seg * 32 + t;
    const size_t o = ((size_t)(b * 128 + j)) * 1024 + c;
    Hs[o] = H;
    H = Ac[o] * H + Uc[o];
  }
  if (seg == 3) hlast[b * 1024 + c] = H;
}

__global__ __launch_bounds__(256) void scan_pass3(
    const f16x2* __restrict__ a, const f16x2* __restrict__ bv,
    const float2* __restrict__ Hs, f16x2* __restrict__ hb) {
  const int c2 = blockIdx.x * 256 + threadIdx.x;
  const int j = blockIdx.y;
  const int b = blockIdx.z;
  const size_t base = ((size_t)(b * 4096 + j * 32)) * 512 + c2;
  float2 H = Hs[((size_t)(b * 128 + j)) * 512 + c2];
  float h0 = H.x, h1 = H.y;
#pragma unroll 8
  for (int t = 0; t < 32; ++t) {
    const size_t o = base + (size_t)t * 512;
    f16x2 at = a[o], bt = bv[o];
    h0 = (float)at[0] * h0 + (float)bt[0];
    h1 = (float)at[1] * h1 + (float)bt[1];
    f16x2 hv; hv[0] = (f16)h0; hv[1] = (f16)h1;
    hb[o] = hv;
  }
}

extern "C" void kernel_launch(void* const* d_in, const int* in_sizes, int n_in,
                              void* d_out, int out_size, void* d_ws,
                              size_t ws_size, hipStream_t stream) {
  const float* x       = (const float*)d_in[0];
  const float* h_prev  = (const float*)d_in[1];
  const float* gate_w  = (const float*)d_in[2];
  const float* gate_b  = (const float*)d_in[3];
  const float* value_w = (const float*)d_in[4];
  const float* out_w   = (const float*)d_in[5];
  float* out = (float*)d_out;

  char* ws = (char*)d_ws;
  // ws layout (bytes), total ~115.3 MB:
  f16*   xh   = (f16*)(ws);                    // 33,554,432  x f16; reused as h
  f16*   wgv  = (f16*)(ws + 33554432);         //  6,291,456  packed weights
  f16*   owb  = (f16*)(ws + 39845888);         //  2,097,152  out_w f16
  f16*   abuf = (f16*)(ws + 41943040);         // 33,554,432  forget gate a
  f16*   bvb  = (f16*)(ws + 75497472);         // 33,554,432  bv = bg*v
  float* Ac   = (float*)(ws + 109051904);      //  2,097,152
  float* Uc   = (float*)(ws + 111149056);      //  2,097,152
  float* Hs   = (float*)(ws + 113246208);      //  2,097,152
  float* hlast = out + 16777216;

  // fused cast + weight packing
  cast_pack<<<10240, 256, 0, stream>>>(x, gate_w, value_w, out_w, xh, wgv,
                                       owb);

  // gates+values GEMM, fused sigmoid + bv epilogue (M=3072 -> 12 m-tiles)
  gemm256<0><<<dim3(768), 512, 0, stream>>>(xh, wgv, gate_b, abuf, bvb, 12);

  // chunked scan (128 chunks x 32)
  scan_pass1<<<dim3(2, 128, 4), 256, 0, stream>>>(
      (const f16x2*)abuf, (const f16x2*)bvb, (float2*)Ac, (float2*)Uc);
  scan_pass2<<<64, 256, 0, stream>>>(Ac, Uc, h_prev, Hs, hlast);
  scan_pass3<<<dim3(2, 128, 4), 256, 0, stream>>>(
      (const f16x2*)abuf, (const f16x2*)bvb, (const float2*)Hs, (f16x2*)xh);

  // output GEMM -> y fp32 (M=1024 -> 4 m-tiles)
  gemm256<1><<<dim3(256), 512, 0, stream>>>(xh, owb, nullptr, out, nullptr, 4);
}

// Round 4
// 352.012 us; speedup vs baseline: 1.0732x; 1.0071x over previous
//
#include <hip/hip_runtime.h>
#include <cstdint>
#include <cstddef>

// GLA layer: B=4, T=4096, D=1024, H=16, S=64
// fp16 pipeline, packed weights (a rows | interleaved bg/v rows).
// GEMMs = 256x256 tile, 8 waves, 16x16x32 MFMA. K-loop = 32 phases
// (one per K-step-32), ROTATED schedule: fragment ds_reads for phase kt+1
// are issued at the END of phase kt (after vmcnt(8)+barrier), so the MFMA
// cluster of each phase starts with frags in flight a barrier ahead;
// gload lead deepened to ~2.3 phases (issue kt+3, wait kt+1). Counted
// lgkmcnt(7/4/0) inside the MFMA cluster; vmcnt never 0 until the tail;
// ONE barrier per phase. LDS = 4-region K-step ring x (A,B), 128 KB,
// XOR-swizzled via pre-swizzled global source. XCD swizzle.
// GEMM1 epilogue: a = sigmoid(.), bv = sigmoid(.)*v (lane-pair shfl),
// LDS-staged f16x8 coalesced stores. Scan: 128 chunks x 32 steps,
// segment-parallel pass2. GEMM2 -> y fp32 direct stores.

typedef _Float16 f16;
typedef _Float16 f16x2 __attribute__((ext_vector_type(2)));
typedef _Float16 f16x8 __attribute__((ext_vector_type(8)));
typedef float    f32x4 __attribute__((ext_vector_type(4)));

__device__ __forceinline__ void gload_lds16(const void* g, void* l) {
  __builtin_amdgcn_global_load_lds(
      (const __attribute__((address_space(1))) void*)g,
      (__attribute__((address_space(3))) void*)l, 16, 0, 0);
}

__device__ __forceinline__ float sigmoidf_(float x) {
  return 1.0f / (1.0f + __expf(-x));
}

// ---------------- fused cast+pack fp32 -> fp16 ----------------
__global__ __launch_bounds__(256) void cast_pack(
    const float* __restrict__ x, const float* __restrict__ gw,
    const float* __restrict__ vw, const float* __restrict__ ow,
    f16* __restrict__ xh, f16* __restrict__ wgv, f16* __restrict__ owb) {
  const int XG = 2097152, GG = 262144, VG = 131072, OG = 131072;
  int id = blockIdx.x * 256 + threadIdx.x;
  const float* src;
  f16* dst;
  if (id < XG) {
    src = x + (size_t)id * 8;
    dst = xh + (size_t)id * 8;
  } else if (id < XG + GG) {
    int g = id - XG;
    int row = g >> 7, col = g & 127;
    int drow = (row < 1024) ? row : (1024 + 2 * (row - 1024));
    src = gw + ((size_t)row << 10) + col * 8;
    dst = wgv + ((size_t)drow << 10) + col * 8;
  } else if (id < XG + GG + VG) {
    int g = id - XG - GG;
    int row = g >> 7, col = g & 127;
    int drow = 1024 + 2 * row + 1;
    src = vw + ((size_t)row << 10) + col * 8;
    dst = wgv + ((size_t)drow << 10) + col * 8;
  } else if (id < XG + GG + VG + OG) {
    int g = id - XG - GG - VG;
    src = ow + (size_t)g * 8;
    dst = owb + (size_t)g * 8;
  } else {
    return;
  }
  float4 v0 = ((const float4*)src)[0], v1 = ((const float4*)src)[1];
  f16x8 o;
  o[0] = (f16)v0.x; o[1] = (f16)v0.y; o[2] = (f16)v0.z; o[3] = (f16)v0.w;
  o[4] = (f16)v1.x; o[5] = (f16)v1.y; o[6] = (f16)v1.z; o[7] = (f16)v1.w;
  *(f16x8*)dst = o;
}

// opaque LDS read: invisible to the compiler's waitcnt alias tracking.
#define DSREAD(dst, addr, off)                                        \
  asm volatile("ds_read_b128 %0, %1 offset:%2"                       \
               : "=v"(dst)                                            \
               : "v"(addr), "i"(off))

#define WAIT_LGKM(n)                                                  \
  asm volatile("s_waitcnt lgkmcnt(" #n ")" ::: "memory");             \
  __builtin_amdgcn_sched_barrier(0)

// ---- 256x256 fp16 MFMA GEMM: C[N,M] = A[N,K] * B[M,K]^T ----
// 8 waves (2 token-halves x 4 channel-quarters), per-wave 128x64 output.
template <int EPI>
__global__ __launch_bounds__(512, 2) void gemm256(
    const f16* __restrict__ A, const f16* __restrict__ Bw,
    const float* __restrict__ gate_b, void* __restrict__ o0v,
    void* __restrict__ o1v, int Mtiles) {
  constexpr int K = 1024;
  __shared__ __align__(16) f16 SH[65536];  // 128 KiB
  f16* LA = SH;          // 4 regions x 8192 f16 (16 KB each)
  f16* LB = SH + 32768;

  const int tid  = threadIdx.x;
  const int lane = tid & 63;
  const int l15  = lane & 15;
  const int oct4 = lane >> 4;   // k-octet within a 32-wide kstep
  const int wid  = tid >> 6;
  const int wr   = wid >> 2;    // 0..1 token half
  const int wc   = wid & 3;     // 0..3 channel quarter

  // bijective XCD swizzle (grid % 8 == 0 for both launches)
  const int nwg = gridDim.x;
  const int bid = blockIdx.x;
  const int swz = (bid & 7) * (nwg >> 3) + (bid >> 3);
  const int m0 = (swz % Mtiles) * 256;
  const int n0 = (swz / Mtiles) * 256;

  // staging: thread covers (row=tid>>2, physOct=(tid&3)^((row>>1)&3))
  const int srow = tid >> 2;
  const int soct = (tid & 3) ^ ((srow >> 1) & 3);
  const f16* Ag = A  + (size_t)(n0 + srow) * K + soct * 8;
  const f16* Bg = Bw + (size_t)(m0 + srow) * K + soct * 8;
  f16* Al = LA + tid * 8;
  f16* Bl = LB + tid * 8;

  // fragment read byte addresses (fswz indep. of mm/nn: +16 rows = +1024 B)
  const int fswz  = oct4 ^ ((l15 >> 1) & 3);
  const unsigned shbase = (unsigned)(uintptr_t)(&SH[0]);
  const int aaddr = (int)shbase + ((wr * 128 + l15) * 4 + fswz) * 16;
  const int baddr = (int)shbase + 65536 + ((wc * 64 + l15) * 4 + fswz) * 16;

  f32x4 acc[8][4];
#pragma unroll
  for (int mm = 0; mm < 8; ++mm)
#pragma unroll
    for (int nn = 0; nn < 4; ++nn)
#pragma unroll
      for (int e = 0; e < 4; ++e) acc[mm][nn][e] = 0.f;

  // stage K-step kt's A+B half-panels into LDS region kt&3 (4 gloads/thread)
#define STAGE_AB(kt)                                                  \
  do {                                                                \
    const f16* sa_ = Ag + (kt) * 32;                                  \
    const f16* sb_ = Bg + (kt) * 32;                                  \
    f16* da_ = Al + ((kt) & 3) * 8192;                                \
    f16* db_ = Bl + ((kt) & 3) * 8192;                                \
    gload_lds16(sa_, da_);                                            \
    gload_lds16(sa_ + 128 * K, da_ + 4096);                           \
    gload_lds16(sb_, db_);                                            \
    gload_lds16(sb_ + 128 * K, db_ + 4096);                           \
  } while (0)

  // prologue: regions 0,1,2 (12 gloads); wait region 0; read frags(0)
  STAGE_AB(0);
  STAGE_AB(1);
  STAGE_AB(2);
  asm volatile("s_waitcnt vmcnt(8)" ::: "memory");
  __builtin_amdgcn_s_barrier();
  asm volatile("" ::: "memory");

  f16x8 af[8], bf[4];
  DSREAD(bf[0], baddr, 0);    DSREAD(bf[1], baddr, 1024);
  DSREAD(bf[2], baddr, 2048); DSREAD(bf[3], baddr, 3072);
  DSREAD(af[0], aaddr, 0);    DSREAD(af[1], aaddr, 1024);
  DSREAD(af[2], aaddr, 2048); DSREAD(af[3], aaddr, 3072);
  DSREAD(af[4], aaddr, 4096); DSREAD(af[5], aaddr, 5120);
  DSREAD(af[6], aaddr, 6144); DSREAD(af[7], aaddr, 7168);

#pragma unroll
  for (int kt = 0; kt < 32; ++kt) {
    // deep prefetch: issue region kt+3 (lead ~2.3 phases)
    if (kt <= 28) STAGE_AB(kt + 3);

    // MFMA(kt): frags issued a barrier ago; counted lgkm waits rarely stall
    __builtin_amdgcn_s_setprio(1);
    WAIT_LGKM(7);  // bf0-3 + af0 ready
#pragma unroll
    for (int nn = 0; nn < 4; ++nn)
      acc[0][nn] = __builtin_amdgcn_mfma_f32_16x16x32_f16(
          af[0], bf[nn], acc[0][nn], 0, 0, 0);
    WAIT_LGKM(4);  // af1-3 ready
#pragma unroll
    for (int mm = 1; mm < 4; ++mm)
#pragma unroll
      for (int nn = 0; nn < 4; ++nn)
        acc[mm][nn] = __builtin_amdgcn_mfma_f32_16x16x32_f16(
            af[mm], bf[nn], acc[mm][nn], 0, 0, 0);
    WAIT_LGKM(0);  // af4-7 ready
#pragma unroll
    for (int mm = 4; mm < 8; ++mm)
#pragma unroll
      for (int nn = 0; nn < 4; ++nn)
        acc[mm][nn] = __builtin_amdgcn_mfma_f32_16x16x32_f16(
            af[mm], bf[nn], acc[mm][nn], 0, 0, 0);
    __builtin_amdgcn_s_setprio(0);
    __builtin_amdgcn_sched_barrier(0);

    if (kt < 31) {
      // guarantee region kt+1 landed (per-wave), then sync all waves,
      // then issue next phase's fragment reads (head start over barrier)
      if (kt <= 28) {
        asm volatile("s_waitcnt vmcnt(8)" ::: "memory");
      } else if (kt == 29) {
        asm volatile("s_waitcnt vmcnt(4)" ::: "memory");
      } else {
        asm volatile("s_waitcnt vmcnt(0)" ::: "memory");
      }
      __builtin_amdgcn_s_barrier();
      asm volatile("" ::: "memory");
      const int ro = ((kt + 1) & 3) * 16384;
      const int aP = aaddr + ro;
      const int bP = baddr + ro;
      DSREAD(bf[0], bP, 0);    DSREAD(bf[1], bP, 1024);
      DSREAD(bf[2], bP, 2048); DSREAD(bf[3], bP, 3072);
      DSREAD(af[0], aP, 0);    DSREAD(af[1], aP, 1024);
      DSREAD(af[2], aP, 2048); DSREAD(af[3], aP, 3072);
      DSREAD(af[4], aP, 4096); DSREAD(af[5], aP, 5120);
      DSREAD(af[6], aP, 6144); DSREAD(af[7], aP, 7168);
    }
  }
#undef STAGE_AB

  // ---------------- epilogues ----------------
  // C/D (16x16): channel col = l15, token row = oct4*4 + r
  if (EPI == 1) {
    float* out = (float*)o0v;
#pragma unroll
    for (int mm = 0; mm < 8; ++mm)
#pragma unroll
      for (int nn = 0; nn < 4; ++nn) {
        const int m = m0 + wc * 64 + nn * 16 + l15;
#pragma unroll
        for (int r = 0; r < 4; ++r) {
          const int n = n0 + wr * 128 + mm * 16 + oct4 * 4 + r;
          out[(size_t)n * 1024 + m] = acc[mm][nn][r];
        }
      }
    return;
  }

  if (m0 < 1024) {
    // forget gate a: sigmoid, stage 128x256 f16 chunks (stride 264)
    float bias[4];
#pragma unroll
    for (int nn = 0; nn < 4; ++nn)
      bias[nn] = gate_b[m0 + wc * 64 + nn * 16 + l15];
    f16* o0 = (f16*)o0v;
#pragma unroll
    for (int ck = 0; ck < 2; ++ck) {
      __builtin_amdgcn_s_barrier();
      asm volatile("" ::: "memory");
      if (wr == ck) {
#pragma unroll
        for (int mm = 0; mm < 8; ++mm)
#pragma unroll
          for (int nn = 0; nn < 4; ++nn) {
            const int ch = wc * 64 + nn * 16 + l15;
#pragma unroll
            for (int r = 0; r < 4; ++r) {
              const int nl = mm * 16 + oct4 * 4 + r;
              SH[nl * 264 + ch] = (f16)sigmoidf_(acc[mm][nn][r] + bias[nn]);
            }
          }
      }
      __builtin_amdgcn_s_barrier();
      asm volatile("" ::: "memory");
#pragma unroll
      for (int j = 0; j < 8; ++j) {
        int s = j * 512 + tid;
        int row = s >> 5, sl = s & 31;
        f16x8 vv = *(const f16x8*)&SH[row * 264 + sl * 8];
        *(f16x8*)(o0 + (size_t)(n0 + ck * 128 + row) * 1024 + m0 + sl * 8) =
            vv;
      }
    }
  } else {
    // bv = sigmoid(bg + bias) * v : even col bg, odd col v (same channel)
    const int c0 = (m0 - 1024) >> 1;
    float biasv[4];
#pragma unroll
    for (int nn = 0; nn < 4; ++nn) {
      const int ml = wc * 64 + nn * 16 + l15;
      biasv[nn] = gate_b[1024 + c0 + (ml >> 1)];
    }
    f16* o1 = (f16*)o1v;
#pragma unroll
    for (int ck = 0; ck < 2; ++ck) {
      __builtin_amdgcn_s_barrier();
      asm volatile("" ::: "memory");
      if (wr == ck) {
#pragma unroll
        for (int mm = 0; mm < 8; ++mm)
#pragma unroll
          for (int nn = 0; nn < 4; ++nn) {
            const int ml = wc * 64 + nn * 16 + l15;
#pragma unroll
            for (int r = 0; r < 4; ++r) {
              float val = acc[mm][nn][r];
              float pv = __shfl_xor(val, 1, 64);  // partner's value
              if (!(lane & 1)) {
                const int nl = mm * 16 + oct4 * 4 + r;
                SH[nl * 136 + (ml >> 1)] =
                    (f16)(sigmoidf_(val + biasv[nn]) * pv);
              }
            }
          }
      }
      __builtin_amdgcn_s_barrier();
      asm volatile("" ::: "memory");
#pragma unroll
      for (int j = 0; j < 4; ++j) {
        int s = j * 512 + tid;
        int row = s >> 4, sl = s & 15;
        f16x8 vv = *(const f16x8*)&SH[row * 136 + sl * 8];
        *(f16x8*)(o1 + (size_t)(n0 + ck * 128 + row) * 1024 + c0 + sl * 8) =
            vv;
      }
    }
  }
}

// ---------------- chunked scan: h_t = a_t*h_{t-1} + bv_t ----------------
// T=4096 = 128 chunks x 32; 2 channels/thread (f16x2).
__global__ __launch_bounds__(256) void scan_pass1(
    const f16x2* __restrict__ a, const f16x2* __restrict__ bv,
    float2* __restrict__ Ac, float2* __restrict__ Uc) {
  const int c2 = blockIdx.x * 256 + threadIdx.x;  // 0..511
  const int j = blockIdx.y;                       // 0..127
  const int b = blockIdx.z;
  const size_t base = ((size_t)(b * 4096 + j * 32)) * 512 + c2;
  float P0 = 1.f, P1 = 1.f, U0 = 0.f, U1 = 0.f;
#pragma unroll 8
  for (int t = 0; t < 32; ++t) {
    const size_t o = base + (size_t)t * 512;
    f16x2 at = a[o], bt = bv[o];
    float a0 = (float)at[0], a1 = (float)at[1];
    P0 *= a0; P1 *= a1;
    U0 = a0 * U0 + (float)bt[0];
    U1 = a1 * U1 + (float)bt[1];
  }
  const size_t o = ((size_t)(b * 128 + j)) * 512 + c2;
  Ac[o] = make_float2(P0, P1);
  Uc[o] = make_float2(U0, U1);
}

// segment-parallel inter-chunk scan: 64 channels x 4 segments of 32 chunks
__global__ __launch_bounds__(256) void scan_pass2(
    const float* __restrict__ Ac, const float* __restrict__ Uc,
    const float* __restrict__ h_prev, float* __restrict__ Hs,
    float* __restrict__ hlast) {
  __shared__ float SA[4][64], SU[4][64];
  const int tid = threadIdx.x;
  const int seg = tid >> 6;            // 0..3
  const int cl  = tid & 63;
  const int ch  = blockIdx.x * 64 + cl;  // 0..4095
  const int b = ch >> 10, c = ch & 1023;
  float A = 1.f, U = 0.f;
  for (int t = 0; t < 32; ++t) {
    const int j = seg * 32 + t;
    const size_t o = ((size_t)(b * 128 + j)) * 1024 + c;
    float av = Ac[o], uv = Uc[o];
    U = av * U + uv;
    A = av * A;
  }
  SA[seg][cl] = A;
  SU[seg][cl] = U;
  __syncthreads();
  float Ae = 1.f, Ue = 0.f;
  for (int s = 0; s < seg; ++s) {
    float av = SA[s][cl], uv = SU[s][cl];
    Ue = av * Ue + uv;
    Ae = av * Ae;
  }
  float H = Ae * h_prev[b * 1024 + c] + Ue;  // state entering my segment
  for (int t = 0; t < 32; ++t) {
    const int j = seg * 32 + t;
    const size_t o = ((size_t)(b * 128 + j)) * 1024 + c;
    Hs[o] = H;
    H = Ac[o] * H + Uc[o];
  }
  if (seg == 3) hlast[b * 1024 + c] = H;
}

__global__ __launch_bounds__(256) void scan_pass3(
    const f16x2* __restrict__ a, const f16x2* __restrict__ bv,
    const float2* __restrict__ Hs, f16x2* __restrict__ hb) {
  const int c2 = blockIdx.x * 256 + threadIdx.x;
  const int j = blockIdx.y;
  const int b = blockIdx.z;
  const size_t base = ((size_t)(b * 4096 + j * 32)) * 512 + c2;
  float2 H = Hs[((size_t)(b * 128 + j)) * 512 + c2];
  float h0 = H.x, h1 = H.y;
#pragma unroll 8
  for (int t = 0; t < 32; ++t) {
    const size_t o = base + (size_t)t * 512;
    f16x2 at = a[o], bt = bv[o];
    h0 = (float)at[0] * h0 + (float)bt[0];
    h1 = (float)at[1] * h1 + (float)bt[1];
    f16x2 hv; hv[0] = (f16)h0; hv[1] = (f16)h1;
    hb[o] = hv;
  }
}

extern "C" void kernel_launch(void* const* d_in, const int* in_sizes, int n_in,
                              void* d_out, int out_size, void* d_ws,
                              size_t ws_size, hipStream_t stream) {
  const float* x       = (const float*)d_in[0];
  const float* h_prev  = (const float*)d_in[1];
  const float* gate_w  = (const float*)d_in[2];
  const float* gate_b  = (const float*)d_in[3];
  const float* value_w = (const float*)d_in[4];
  const float* out_w   = (const float*)d_in[5];
  float* out = (float*)d_out;

  char* ws = (char*)d_ws;
  // ws layout (bytes), total ~115.3 MB:
  f16*   xh   = (f16*)(ws);                    // 33,554,432  x f16; reused as h
  f16*   wgv  = (f16*)(ws + 33554432);         //  6,291,456  packed weights
  f16*   owb  = (f16*)(ws + 39845888);         //  2,097,152  out_w f16
  f16*   abuf = (f16*)(ws + 41943040);         // 33,554,432  forget gate a
  f16*   bvb  = (f16*)(ws + 75497472);         // 33,554,432  bv = bg*v
  float* Ac   = (float*)(ws + 109051904);      //  2,097,152
  float* Uc   = (float*)(ws + 111149056);      //  2,097,152
  float* Hs   = (float*)(ws + 113246208);      //  2,097,152
  float* hlast = out + 16777216;

  // fused cast + weight packing
  cast_pack<<<10240, 256, 0, stream>>>(x, gate_w, value_w, out_w, xh, wgv,
                                       owb);

  // gates+values GEMM, fused sigmoid + bv epilogue (M=3072 -> 12 m-tiles)
  gemm256<0><<<dim3(768), 512, 0, stream>>>(xh, wgv, gate_b, abuf, bvb, 12);

  // chunked scan (128 chunks x 32)
  scan_pass1<<<dim3(2, 128, 4), 256, 0, stream>>>(
      (const f16x2*)abuf, (const f16x2*)bvb, (float2*)Ac, (float2*)Uc);
  scan_pass2<<<64, 256, 0, stream>>>(Ac, Uc, h_prev, Hs, hlast);
  scan_pass3<<<dim3(2, 128, 4), 256, 0, stream>>>(
      (const f16x2*)abuf, (const f16x2*)bvb, (const float2*)Hs, (f16x2*)xh);

  // output GEMM -> y fp32 (M=1024 -> 4 m-tiles)
  gemm256<1><<<dim3(256), 512, 0, stream>>>(xh, owb, nullptr, out, nullptr, 4);
}